// Round 3
// baseline (697.532 us; speedup 1.0000x reference)
//
#include <hip/hip_runtime.h>

#define S 4096
#define C 2048
#define H 16
#define D 128
#define EPS 1.1920929e-07f
#define SCALE 0.08838834764831845f  // 1/sqrt(128)

typedef __attribute__((ext_vector_type(8))) short short8;            // 8 bf16 (MFMA x32 A/B)
typedef __attribute__((ext_vector_type(4))) float f32x4;             // MFMA C/D
typedef __attribute__((ext_vector_type(4))) unsigned short ushort4v; // 4 bf16 (MFMA x16 A/B)

#if __has_builtin(__builtin_amdgcn_mfma_f32_16x16x16bf16_1k)
#define HAVE_MFMA16 1
#else
#define HAVE_MFMA16 0
#endif

__device__ __forceinline__ unsigned short f2bf(float f) {
  unsigned int u = __builtin_bit_cast(unsigned int, f);
  u += 0x7fff + ((u >> 16) & 1);  // RNE
  return (unsigned short)(u >> 16);
}
__device__ __forceinline__ float bf2f(unsigned short v) {
  unsigned int u = ((unsigned int)v) << 16;
  return __builtin_bit_cast(float, u);
}
__device__ __forceinline__ unsigned int pkbf(float a, float b) {
  return (unsigned int)f2bf(a) | ((unsigned int)f2bf(b) << 16);
}
// async global->LDS, 16B/lane; LDS dest = wave-uniform base + lane*16
__device__ __forceinline__ void gld16(const unsigned short* g, unsigned short* l) {
  __builtin_amdgcn_global_load_lds(
      (const __attribute__((address_space(1))) unsigned int*)g,
      (__attribute__((address_space(3))) unsigned int*)l, 16, 0, 0);
}

// ---------------- fp32 -> bf16 converts ----------------
__global__ void cvt_kernel(const float* __restrict__ src,
                           unsigned short* __restrict__ dst, int n) {
  int i = (blockIdx.x * 256 + threadIdx.x) * 4;
  if (i >= n) return;
  float4 v = *(const float4*)(src + i);
  ushort4 o;
  o.x = f2bf(v.x); o.y = f2bf(v.y); o.z = f2bf(v.z); o.w = f2bf(v.w);
  *(ushort4*)(dst + i) = o;
}
__global__ void cvtw_kernel(const float* __restrict__ w0, const float* __restrict__ w1,
                            const float* __restrict__ w2, const float* __restrict__ w3,
                            unsigned short* __restrict__ dst) {
  const float* srcs[4] = {w0, w1, w2, w3};
  const float* src = srcs[blockIdx.y];
  int i = (blockIdx.x * 256 + threadIdx.x) * 4;
  float4 v = *(const float4*)(src + i);
  ushort4 o;
  o.x = f2bf(v.x); o.y = f2bf(v.y); o.z = f2bf(v.z); o.w = f2bf(v.w);
  *(ushort4*)(dst + (size_t)blockIdx.y * C * C + i) = o;
}
__global__ void bias_concat(const float* __restrict__ bq, const float* __restrict__ bk,
                            const float* __restrict__ bv, float* __restrict__ dst) {
  int i = blockIdx.x * 256 + threadIdx.x;  // 0..6143
  const float* s = (i < C) ? bq : ((i < 2 * C) ? bk : bv);
  dst[i] = s[i & (C - 1)];
}

// ---------------- bf16 GEMM: out[m][n] = sum_k A[m][k]*B[n][k] + bias[n]
// mode 0: fp32 out [M][N].
// mode 1 (QKV): fused epilogue. Global head gh = n>>7: gh<16 -> q (rmsnorm+rope+scale),
//   gh<32 -> k (rmsnorm+rope), else v (transpose to [h][d][s]).
__global__ __launch_bounds__(256) void gemm_bt(const unsigned short* __restrict__ A,
                                               const unsigned short* __restrict__ B,
                                               const float* __restrict__ bias,
                                               void* __restrict__ out,
                                               const float* __restrict__ rope,
                                               const float* __restrict__ qn_w,
                                               const float* __restrict__ kn_w,
                                               unsigned short* __restrict__ hq,
                                               unsigned short* __restrict__ hvt,
                                               int N, int mode) {
  __shared__ __align__(16) unsigned short U[128 * 132];  // union: main loop uses first 32KB
  unsigned short* Al = U;             // 128*64
  unsigned short* Bl = U + 128 * 64;  // 128*64
  const int t = threadIdx.x, w = t >> 6, lane = t & 63;
  const int lq = lane & 15, quad = lane >> 4;
  const int wm = w & 1, wn = w >> 1;
  const int m0 = blockIdx.y * 128, n0 = blockIdx.x * 128;
  f32x4 acc[4][4] = {};
  float biasv[4];
#pragma unroll
  for (int nt = 0; nt < 4; nt++) biasv[nt] = bias[n0 + wn * 64 + nt * 16 + lq];
  const int sr = lane >> 3, sg = lane & 7;
  for (int k0 = 0; k0 < C; k0 += 64) {
    __syncthreads();
#pragma unroll
    for (int p = 0; p < 4; p++) {
      int row = w * 32 + p * 8 + sr;
      int c = sg ^ (row & 7);  // swizzle on global source; LDS dest lane-linear
      gld16(A + (size_t)(m0 + row) * C + k0 + c * 8, &Al[(w * 32 + p * 8) * 64]);
      gld16(B + (size_t)(n0 + row) * C + k0 + c * 8, &Bl[(w * 32 + p * 8) * 64]);
    }
    __syncthreads();
#pragma unroll
    for (int ks = 0; ks < 2; ks++) {
      short8 af[4], bf[4];
#pragma unroll
      for (int mt = 0; mt < 4; mt++) {
        int row = wm * 64 + mt * 16 + lq;
        af[mt] = *(const short8*)&Al[row * 64 + ((ks * 4 + quad) ^ (lq & 7)) * 8];
      }
#pragma unroll
      for (int nt = 0; nt < 4; nt++) {
        int row = wn * 64 + nt * 16 + lq;
        bf[nt] = *(const short8*)&Bl[row * 64 + ((ks * 4 + quad) ^ (lq & 7)) * 8];
      }
#pragma unroll
      for (int mt = 0; mt < 4; mt++)
#pragma unroll
        for (int nt = 0; nt < 4; nt++)
          acc[mt][nt] = __builtin_amdgcn_mfma_f32_16x16x32_bf16(af[mt], bf[nt], acc[mt][nt], 0, 0, 0);
    }
  }

  if (mode == 0) {
#pragma unroll
    for (int mt = 0; mt < 4; mt++)
#pragma unroll
      for (int nt = 0; nt < 4; nt++) {
        int n = n0 + wn * 64 + nt * 16 + lq;
#pragma unroll
        for (int r = 0; r < 4; r++) {
          int m = m0 + wm * 64 + mt * 16 + quad * 4 + r;  // C/D: col=lane&15, row=quad*4+r
          ((float*)out)[(size_t)m * N + n] = acc[mt][nt][r] + biasv[nt];
        }
      }
    return;
  }

  // ---- mode 1 fused epilogue ----
  const int gh = n0 >> 7;  // 0..47
  __syncthreads();  // done reading Al/Bl
  if (gh < 32) {
    // bounce [m][d] bf16, stride 132
#pragma unroll
    for (int mt = 0; mt < 4; mt++)
#pragma unroll
      for (int nt = 0; nt < 4; nt++) {
        int dloc = wn * 64 + nt * 16 + lq;
#pragma unroll
        for (int r = 0; r < 4; r++) {
          int mloc = wm * 64 + mt * 16 + quad * 4 + r;
          U[mloc * 132 + dloc] = f2bf(acc[mt][nt][r] + biasv[nt]);
        }
      }
    __syncthreads();
    // finish: 2 threads per row; thread t -> row m=t>>1, d-half hf=t&1
    const int m = t >> 1, hf = t & 1;
    const int s = m0 + m;
    unsigned short xv[64];
#pragma unroll
    for (int i = 0; i < 8; i++)
      *(short8*)(xv + i * 8) = *(const short8*)&U[m * 132 + hf * 64 + i * 8];
    const float* nw = (gh < 16) ? qn_w : kn_w;
    float ss = 0.0f;
#pragma unroll
    for (int i = 0; i < 64; i++) { float x = bf2f(xv[i]); ss += x * x; }
    ss += __shfl_xor(ss, 1);
    float inv = rsqrtf(ss * (1.0f / 128.0f) + EPS);
    if (gh < 16) inv *= SCALE;
    unsigned int ow[32];
#pragma unroll
    for (int jj = 0; jj < 32; jj++) {
      int dl = hf * 64 + 2 * jj;
      float x0 = bf2f(xv[2 * jj]) * inv * nw[dl];
      float x1 = bf2f(xv[2 * jj + 1]) * inv * nw[dl + 1];
      float4 r4 = *(const float4*)(rope + (size_t)s * 256 + (size_t)(dl >> 1) * 4);
      ow[jj] = pkbf(r4.x * x0 + r4.y * x1, r4.z * x0 + r4.w * x1);
    }
    unsigned short* dst = hq + ((size_t)gh * S + s) * D + hf * 64;
#pragma unroll
    for (int i = 0; i < 8; i++)
      *(uint4*)(dst + i * 8) = *(uint4*)((unsigned short*)ow + i * 8);
  } else {
    // v: bounce transposed [d][m] bf16, stride 132
#pragma unroll
    for (int mt = 0; mt < 4; mt++)
#pragma unroll
      for (int nt = 0; nt < 4; nt++) {
        int dloc = wn * 64 + nt * 16 + lq;
#pragma unroll
        for (int r = 0; r < 4; r++) {
          int mloc = wm * 64 + mt * 16 + quad * 4 + r;
          U[dloc * 132 + mloc] = f2bf(acc[mt][nt][r] + biasv[nt]);
        }
      }
    __syncthreads();
    const int d = t >> 1, sh = t & 1;
    unsigned short cv[64];
#pragma unroll
    for (int i = 0; i < 8; i++)
      *(short8*)(cv + i * 8) = *(const short8*)&U[d * 132 + sh * 64 + i * 8];
    unsigned short* dst = hvt + ((size_t)(gh - 32) * D + d) * S + m0 + sh * 64;
#pragma unroll
    for (int i = 0; i < 8; i++)
      *(uint4*)(dst + i * 8) = *(uint4*)(cv + i * 8);
  }
}

// ---------------- flash attention, BM=32 q-rows per wave, BN=64 j per tile.
// S^T = K·Q^T so softmax rows sit on lane&15 and P is born in x16 A-layout.
__global__ __launch_bounds__(256, 2) void flash_kernel(const unsigned short* __restrict__ qh,
                                                       const unsigned short* __restrict__ kh,
                                                       const unsigned short* __restrict__ vt,
                                                       unsigned short* __restrict__ ao) {
  __shared__ __align__(16) unsigned short Klds[64 * 128];  // [j][d], swizzled
  __shared__ __align__(16) unsigned short Vlds[128 * 64];  // [d][j], swizzled
#if !HAVE_MFMA16
  __shared__ __align__(16) unsigned short Plds[4 * 16 * 72];
#endif
  const int h = blockIdx.y, i0 = blockIdx.x * 128;
  const int t = threadIdx.x, w = t >> 6, lane = t & 63;
  const int lq = lane & 15, quad = lane >> 4;

  // Q as MFMA B-operand: n=lq (q row), k=quad*8+j (d). scale pre-folded in gemm epilogue.
  const unsigned short* Qbase = qh + ((size_t)h * S + i0 + w * 32 + lq) * D;
  short8 qfrag[2][4];
#pragma unroll
  for (int qi = 0; qi < 2; qi++)
#pragma unroll
    for (int kt = 0; kt < 4; kt++)
      qfrag[qi][kt] = *(const short8*)(Qbase + (size_t)qi * 16 * D + kt * 32 + quad * 8);

  f32x4 oacc[2][8] = {};
  float mrun[2] = {-1e30f, -1e30f}, lrun[2] = {0.0f, 0.0f};
  const unsigned short* Kbase = kh + (size_t)h * S * D;
  const unsigned short* Vbase = vt + (size_t)h * D * S;

  const int kr = lane >> 4, kg = lane & 15;  // K stage: 4 rows/call
  const int vr = lane >> 3, vg = lane & 7;   // V stage: 8 rows/call

  for (int j0 = 0; j0 < S; j0 += 64) {
    __syncthreads();
#pragma unroll
    for (int p = 0; p < 4; p++) {
      int krow = w * 16 + p * 4 + kr;
      gld16(Kbase + (size_t)(j0 + krow) * D + (kg ^ (krow & 7)) * 8,
            &Klds[(w * 16 + p * 4) * 128]);
      int vrow = w * 32 + p * 8 + vr;
      gld16(Vbase + (size_t)vrow * S + j0 + (vg ^ (vrow & 7)) * 8,
            &Vlds[(w * 32 + p * 8) * 64]);
    }
    __syncthreads();

    // S^T = K·Q^T : sacc[qi][nt][r] = S[q=lq(+16qi)][j = j0 + nt*16 + quad*4 + r]
    f32x4 sacc[2][4] = {};
#pragma unroll
    for (int kt = 0; kt < 4; kt++)
#pragma unroll
      for (int nt = 0; nt < 4; nt++) {
        int row = nt * 16 + lq;
        short8 af = *(const short8*)&Klds[row * 128 + ((kt * 4 + quad) ^ (lq & 7)) * 8];
        sacc[0][nt] = __builtin_amdgcn_mfma_f32_16x16x32_bf16(af, qfrag[0][kt], sacc[0][nt], 0, 0, 0);
        sacc[1][nt] = __builtin_amdgcn_mfma_f32_16x16x32_bf16(af, qfrag[1][kt], sacc[1][nt], 0, 0, 0);
      }

    ushort4v afp[2][4];
#pragma unroll
    for (int qi = 0; qi < 2; qi++) {
      float vmax = sacc[qi][0][0];
#pragma unroll
      for (int nt = 0; nt < 4; nt++)
#pragma unroll
        for (int r = 0; r < 4; r++) vmax = fmaxf(vmax, sacc[qi][nt][r]);
      vmax = fmaxf(vmax, __shfl_xor(vmax, 16));
      vmax = fmaxf(vmax, __shfl_xor(vmax, 32));
      float mnew = fmaxf(mrun[qi], vmax);
      float alpha = __expf(mrun[qi] - mnew);
      float rsum = 0.0f;
#pragma unroll
      for (int nt = 0; nt < 4; nt++) {
        float e0 = __expf(sacc[qi][nt][0] - mnew);
        float e1 = __expf(sacc[qi][nt][1] - mnew);
        float e2 = __expf(sacc[qi][nt][2] - mnew);
        float e3 = __expf(sacc[qi][nt][3] - mnew);
        rsum += (e0 + e1) + (e2 + e3);
        ushort4v p4;
        p4.x = f2bf(e0); p4.y = f2bf(e1); p4.z = f2bf(e2); p4.w = f2bf(e3);
        afp[qi][nt] = p4;
      }
      rsum += __shfl_xor(rsum, 16);
      rsum += __shfl_xor(rsum, 32);
      lrun[qi] = lrun[qi] * alpha + rsum;
      mrun[qi] = mnew;
#pragma unroll
      for (int r = 0; r < 4; r++) {
        float ar = __shfl(alpha, quad * 4 + r);
#pragma unroll
        for (int dt = 0; dt < 8; dt++) oacc[qi][dt][r] *= ar;
      }
    }

#if HAVE_MFMA16
    // P in A-layout for 16x16x16: A[m=lq][k=quad*4+j]; V-frag read shared by both qi
#pragma unroll
    for (int ntk = 0; ntk < 4; ntk++) {
      int g = 2 * ntk + (quad >> 1);
      int go = (quad & 1) * 4;
#pragma unroll
      for (int dt = 0; dt < 8; dt++) {
        int row = dt * 16 + lq;
        ushort4v bf = *(const ushort4v*)&Vlds[row * 64 + (g ^ (row & 7)) * 8 + go];
        oacc[0][dt] = __builtin_amdgcn_mfma_f32_16x16x16bf16_1k(afp[0][ntk], bf, oacc[0][dt], 0, 0, 0);
        oacc[1][dt] = __builtin_amdgcn_mfma_f32_16x16x16bf16_1k(afp[1][ntk], bf, oacc[1][dt], 0, 0, 0);
      }
    }
#else
    // fallback: wave-local LDS round trip to x32 A-layout
    unsigned short* Pw = Plds + w * 16 * 72;
#pragma unroll
    for (int qi = 0; qi < 2; qi++) {
#pragma unroll
      for (int nt = 0; nt < 4; nt++)
        *(ushort4v*)&Pw[lq * 72 + nt * 16 + quad * 4] = afp[qi][nt];
#pragma unroll
      for (int kt = 0; kt < 2; kt++) {
        short8 af = *(const short8*)&Pw[lq * 72 + kt * 32 + quad * 8];
#pragma unroll
        for (int dt = 0; dt < 8; dt++) {
          int row = dt * 16 + lq;
          short8 bf = *(const short8*)&Vlds[row * 64 + ((kt * 4 + quad) ^ (lq & 7)) * 8];
          oacc[qi][dt] = __builtin_amdgcn_mfma_f32_16x16x32_bf16(af, bf, oacc[qi][dt], 0, 0, 0);
        }
      }
    }
#endif
  }

  float il[2][4];
#pragma unroll
  for (int qi = 0; qi < 2; qi++)
#pragma unroll
    for (int r = 0; r < 4; r++) il[qi][r] = 1.0f / __shfl(lrun[qi], quad * 4 + r);
#pragma unroll
  for (int qi = 0; qi < 2; qi++)
#pragma unroll
    for (int dt = 0; dt < 8; dt++)
#pragma unroll
      for (int r = 0; r < 4; r++)
        ao[(size_t)(i0 + w * 32 + qi * 16 + quad * 4 + r) * C + h * 128 + dt * 16 + lq] =
            f2bf(oacc[qi][dt][r] * il[qi][r]);
}

extern "C" void kernel_launch(void* const* d_in, const int* in_sizes, int n_in,
                              void* d_out, int out_size, void* d_ws, size_t ws_size,
                              hipStream_t stream) {
  const float* x    = (const float*)d_in[0];
  const float* rope = (const float*)d_in[1];
  const float* Wq   = (const float*)d_in[2];
  const float* bq   = (const float*)d_in[3];
  const float* Wk   = (const float*)d_in[4];
  const float* bk   = (const float*)d_in[5];
  const float* Wv   = (const float*)d_in[6];
  const float* bv   = (const float*)d_in[7];
  const float* qn_w = (const float*)d_in[8];
  const float* kn_w = (const float*)d_in[9];
  const float* Wo   = (const float*)d_in[10];
  const float* bo   = (const float*)d_in[11];
  float* out = (float*)d_out;

  unsigned short* xb  = (unsigned short*)d_ws;      // S*C
  unsigned short* wqb = xb + (size_t)S * C;         // 4*C*C (Wq,Wk,Wv,Wo contiguous)
  unsigned short* wob = wqb + (size_t)3 * C * C;
  unsigned short* qh  = wqb + (size_t)4 * C * C;    // q heads [16][S][D]
  unsigned short* kh  = qh + (size_t)S * C;         // k heads [16][S][D]
  unsigned short* vt  = kh + (size_t)S * C;         // v transposed [16][D][S]
  unsigned short* ao  = vt + (size_t)S * C;         // [S][C]
  float* bqkv = (float*)(ao + (size_t)S * C);       // 6144 floats

  cvt_kernel<<<S * C / 1024, 256, 0, stream>>>(x, xb, S * C);
  cvtw_kernel<<<dim3(C * C / 1024, 4), 256, 0, stream>>>(Wq, Wk, Wv, Wo, wqb);
  bias_concat<<<3 * C / 256, 256, 0, stream>>>(bq, bk, bv, bqkv);

  // fused QKV projection + rmsnorm + rope + v-transpose epilogue
  gemm_bt<<<dim3(3 * C / 128, S / 128), 256, 0, stream>>>(
      xb, wqb, bqkv, nullptr, rope, qn_w, kn_w, qh, vt, 3 * C, 1);

  flash_kernel<<<dim3(S / 128, H), 256, 0, stream>>>(qh, kh, vt, ao);

  gemm_bt<<<dim3(C / 128, S / 128), 256, 0, stream>>>(
      ao, wob, bo, (void*)out, nullptr, nullptr, nullptr, nullptr, nullptr, C, 0);
}

// Round 4
// 559.243 us; speedup vs baseline: 1.2473x; 1.2473x over previous
//
#include <hip/hip_runtime.h>

#define S 4096
#define C 2048
#define H 16
#define D 128
#define EPS 1.1920929e-07f
#define SCALE 0.08838834764831845f  // 1/sqrt(128)

typedef __attribute__((ext_vector_type(8))) short short8;            // 8 bf16 (MFMA x32 A/B)
typedef __attribute__((ext_vector_type(4))) float f32x4;             // MFMA C/D
typedef __attribute__((ext_vector_type(4))) unsigned short ushort4v; // 4 bf16 (MFMA x16 A/B)

#if __has_builtin(__builtin_amdgcn_mfma_f32_16x16x16bf16_1k)
#define HAVE_MFMA16 1
#else
#define HAVE_MFMA16 0
#endif

__device__ __forceinline__ unsigned short f2bf(float f) {
  unsigned int u = __builtin_bit_cast(unsigned int, f);
  u += 0x7fff + ((u >> 16) & 1);  // RNE
  return (unsigned short)(u >> 16);
}
__device__ __forceinline__ float bf2f(unsigned short v) {
  unsigned int u = ((unsigned int)v) << 16;
  return __builtin_bit_cast(float, u);
}
__device__ __forceinline__ unsigned int pkbf(float a, float b) {
  return (unsigned int)f2bf(a) | ((unsigned int)f2bf(b) << 16);
}
// async global->LDS, 16B/lane; LDS dest = wave-uniform base + lane*16
__device__ __forceinline__ void gld16(const unsigned short* g, unsigned short* l) {
  __builtin_amdgcn_global_load_lds(
      (const __attribute__((address_space(1))) unsigned int*)g,
      (__attribute__((address_space(3))) unsigned int*)l, 16, 0, 0);
}

// ---------------- fp32 -> bf16 converts ----------------
__global__ void cvt_kernel(const float* __restrict__ src,
                           unsigned short* __restrict__ dst, int n) {
  int i = (blockIdx.x * 256 + threadIdx.x) * 4;
  if (i >= n) return;
  float4 v = *(const float4*)(src + i);
  ushort4 o;
  o.x = f2bf(v.x); o.y = f2bf(v.y); o.z = f2bf(v.z); o.w = f2bf(v.w);
  *(ushort4*)(dst + i) = o;
}
__global__ void cvtw_kernel(const float* __restrict__ w0, const float* __restrict__ w1,
                            const float* __restrict__ w2, const float* __restrict__ w3,
                            unsigned short* __restrict__ dst) {
  const float* srcs[4] = {w0, w1, w2, w3};
  const float* src = srcs[blockIdx.y];
  int i = (blockIdx.x * 256 + threadIdx.x) * 4;
  float4 v = *(const float4*)(src + i);
  ushort4 o;
  o.x = f2bf(v.x); o.y = f2bf(v.y); o.z = f2bf(v.z); o.w = f2bf(v.w);
  *(ushort4*)(dst + (size_t)blockIdx.y * C * C + i) = o;
}
__global__ void bias_concat(const float* __restrict__ bq, const float* __restrict__ bk,
                            const float* __restrict__ bv, float* __restrict__ dst) {
  int i = blockIdx.x * 256 + threadIdx.x;  // 0..6143
  const float* s = (i < C) ? bq : ((i < 2 * C) ? bk : bv);
  dst[i] = s[i & (C - 1)];
}

// ---------------- bf16 GEMM (m97 structure): out[m][n] = sum_k A[m][k]*B[n][k] + bias[n]
// M=S fixed, K=C fixed, N param. mode 0: fp32 [M][N]; mode 1: bf16 head layout [n>>7][m][n&127].
__global__ __launch_bounds__(256) void gemm_bt(const unsigned short* __restrict__ A,
                                               const unsigned short* __restrict__ B,
                                               const float* __restrict__ bias,
                                               void* __restrict__ out, int N, int mode) {
  __shared__ __align__(16) unsigned short Al[128 * 64];  // unpadded, XOR-swizzled groups
  __shared__ __align__(16) unsigned short Bl[128 * 64];
  const int t = threadIdx.x, w = t >> 6, lane = t & 63;
  const int lq = lane & 15, quad = lane >> 4;
  const int wm = w & 1, wn = w >> 1;
  const int m0 = blockIdx.y * 128, n0 = blockIdx.x * 128;
  f32x4 acc[4][4] = {};
  float biasv[4];
#pragma unroll
  for (int nt = 0; nt < 4; nt++) biasv[nt] = bias[n0 + wn * 64 + nt * 16 + lq];
  const int sr = lane >> 3, sg = lane & 7;
  for (int k0 = 0; k0 < C; k0 += 64) {
    __syncthreads();
#pragma unroll
    for (int p = 0; p < 4; p++) {
      int row = w * 32 + p * 8 + sr;
      int c = sg ^ (row & 7);  // swizzle on the global source; LDS dest lane-linear
      gld16(A + (size_t)(m0 + row) * C + k0 + c * 8, &Al[(w * 32 + p * 8) * 64]);
      gld16(B + (size_t)(n0 + row) * C + k0 + c * 8, &Bl[(w * 32 + p * 8) * 64]);
    }
    __syncthreads();
#pragma unroll
    for (int ks = 0; ks < 2; ks++) {
      short8 af[4], bf[4];
#pragma unroll
      for (int mt = 0; mt < 4; mt++) {
        int row = wm * 64 + mt * 16 + lq;
        af[mt] = *(const short8*)&Al[row * 64 + ((ks * 4 + quad) ^ (lq & 7)) * 8];
      }
#pragma unroll
      for (int nt = 0; nt < 4; nt++) {
        int row = wn * 64 + nt * 16 + lq;
        bf[nt] = *(const short8*)&Bl[row * 64 + ((ks * 4 + quad) ^ (lq & 7)) * 8];
      }
#pragma unroll
      for (int mt = 0; mt < 4; mt++)
#pragma unroll
        for (int nt = 0; nt < 4; nt++)
          acc[mt][nt] = __builtin_amdgcn_mfma_f32_16x16x32_bf16(af[mt], bf[nt], acc[mt][nt], 0, 0, 0);
    }
  }
#pragma unroll
  for (int mt = 0; mt < 4; mt++)
#pragma unroll
    for (int nt = 0; nt < 4; nt++) {
      int n = n0 + wn * 64 + nt * 16 + lq;
#pragma unroll
      for (int r = 0; r < 4; r++) {
        int m = m0 + wm * 64 + mt * 16 + quad * 4 + r;  // C/D: col=lane&15, row=quad*4+r
        float v = acc[mt][nt][r] + biasv[nt];
        if (mode == 0) ((float*)out)[(size_t)m * N + n] = v;
        else ((unsigned short*)out)[(size_t)(n >> 7) * S * D + (size_t)m * D + (n & 127)] = f2bf(v);
      }
    }
}

// ---------------- fused RMSNorm + rotary, in place on [H][S][D] bf16 ----------------
__global__ __launch_bounds__(256) void rmsrope_kernel(unsigned short* __restrict__ io,
                                                      const float* __restrict__ wgt,
                                                      const float* __restrict__ rope,
                                                      float scale) {
  int wid = (blockIdx.x * 256 + threadIdx.x) >> 6;  // wave id = h*S + s
  int lane = threadIdx.x & 63;
  int s = wid & (S - 1);
  unsigned short* row = io + (size_t)wid * D;
  unsigned int pr = *(unsigned int*)(row + lane * 2);
  float a = bf2f((unsigned short)(pr & 0xffff));
  float b = bf2f((unsigned short)(pr >> 16));
  float ss = a * a + b * b;
  for (int m = 1; m < 64; m <<= 1) ss += __shfl_xor(ss, m);
  float inv = rsqrtf(ss * (1.0f / 128.0f) + EPS);
  float2 wv = *(const float2*)(wgt + lane * 2);
  float an = a * inv * wv.x, bn = b * inv * wv.y;
  float4 r = *(const float4*)(rope + (size_t)s * 256 + lane * 4);
  float o0 = (r.x * an + r.y * bn) * scale;
  float o1 = (r.z * an + r.w * bn) * scale;
  *(unsigned int*)(row + lane * 2) = pkbf(o0, o1);
}

// ---------------- V transpose: [H][S][D] -> [H][D][S] ----------------
__global__ __launch_bounds__(256) void transpose_v(const unsigned short* __restrict__ vh,
                                                   unsigned short* __restrict__ vt) {
  __shared__ unsigned short tile[64][72];
  int h = blockIdx.z, s0 = blockIdx.x * 64, d0 = blockIdx.y * 64;
  int t = threadIdx.x;
  for (int p = 0; p < 2; p++) {
    int sl = p * 32 + (t >> 3);
    int d8 = (t & 7) * 8;
    *(uint4*)&tile[sl][d8] = *(const uint4*)(vh + ((size_t)h * S + s0 + sl) * D + d0 + d8);
  }
  __syncthreads();
  for (int p = 0; p < 2; p++) {
    int dl = p * 32 + (t >> 3);
    int s8 = (t & 7) * 8;
    unsigned short vals[8];
    for (int i = 0; i < 8; i++) vals[i] = tile[s8 + i][dl];
    *(uint4*)(vt + ((size_t)h * D + d0 + dl) * S + s0 + s8) = *(uint4*)vals;
  }
}

// ---------------- flash attention, BM=32 q-rows per wave, BN=64 j per tile.
// S^T = K·Q^T so softmax rows sit on lane&15 and P is born in x16 A-layout.
__global__ __launch_bounds__(256, 2) void flash_kernel(const unsigned short* __restrict__ qh,
                                                       const unsigned short* __restrict__ kh,
                                                       const unsigned short* __restrict__ vt,
                                                       unsigned short* __restrict__ ao) {
  __shared__ __align__(16) unsigned short Klds[64 * 128];  // [j][d], swizzled
  __shared__ __align__(16) unsigned short Vlds[128 * 64];  // [d][j], swizzled
#if !HAVE_MFMA16
  __shared__ __align__(16) unsigned short Plds[4 * 16 * 72];
#endif
  const int h = blockIdx.y, i0 = blockIdx.x * 128;
  const int t = threadIdx.x, w = t >> 6, lane = t & 63;
  const int lq = lane & 15, quad = lane >> 4;

  // Q as MFMA B-operand: n=lq (q row), k=quad*8+j (d). scale pre-folded by rmsrope.
  const unsigned short* Qbase = qh + ((size_t)h * S + i0 + w * 32 + lq) * D;
  short8 qfrag[2][4];
#pragma unroll
  for (int qi = 0; qi < 2; qi++)
#pragma unroll
    for (int kt = 0; kt < 4; kt++)
      qfrag[qi][kt] = *(const short8*)(Qbase + (size_t)qi * 16 * D + kt * 32 + quad * 8);

  f32x4 oacc[2][8] = {};
  float mrun[2] = {-1e30f, -1e30f}, lrun[2] = {0.0f, 0.0f};
  const unsigned short* Kbase = kh + (size_t)h * S * D;
  const unsigned short* Vbase = vt + (size_t)h * D * S;

  const int kr = lane >> 4, kg = lane & 15;  // K stage: 4 rows/call
  const int vr = lane >> 3, vg = lane & 7;   // V stage: 8 rows/call

  for (int j0 = 0; j0 < S; j0 += 64) {
    __syncthreads();
#pragma unroll
    for (int p = 0; p < 4; p++) {
      int krow = w * 16 + p * 4 + kr;
      gld16(Kbase + (size_t)(j0 + krow) * D + (kg ^ (krow & 7)) * 8,
            &Klds[(w * 16 + p * 4) * 128]);
      int vrow = w * 32 + p * 8 + vr;
      gld16(Vbase + (size_t)vrow * S + j0 + (vg ^ (vrow & 7)) * 8,
            &Vlds[(w * 32 + p * 8) * 64]);
    }
    __syncthreads();

    // S^T = K·Q^T : sacc[qi][nt][r] = S[q=lq(+16qi)][j = j0 + nt*16 + quad*4 + r]
    f32x4 sacc[2][4] = {};
#pragma unroll
    for (int kt = 0; kt < 4; kt++)
#pragma unroll
      for (int nt = 0; nt < 4; nt++) {
        int row = nt * 16 + lq;
        short8 af = *(const short8*)&Klds[row * 128 + ((kt * 4 + quad) ^ (lq & 7)) * 8];
        sacc[0][nt] = __builtin_amdgcn_mfma_f32_16x16x32_bf16(af, qfrag[0][kt], sacc[0][nt], 0, 0, 0);
        sacc[1][nt] = __builtin_amdgcn_mfma_f32_16x16x32_bf16(af, qfrag[1][kt], sacc[1][nt], 0, 0, 0);
      }

    ushort4v afp[2][4];
#pragma unroll
    for (int qi = 0; qi < 2; qi++) {
      float vmax = sacc[qi][0][0];
#pragma unroll
      for (int nt = 0; nt < 4; nt++)
#pragma unroll
        for (int r = 0; r < 4; r++) vmax = fmaxf(vmax, sacc[qi][nt][r]);
      vmax = fmaxf(vmax, __shfl_xor(vmax, 16));
      vmax = fmaxf(vmax, __shfl_xor(vmax, 32));
      float mnew = fmaxf(mrun[qi], vmax);
      float alpha = __expf(mrun[qi] - mnew);
      float rsum = 0.0f;
#pragma unroll
      for (int nt = 0; nt < 4; nt++) {
        float e0 = __expf(sacc[qi][nt][0] - mnew);
        float e1 = __expf(sacc[qi][nt][1] - mnew);
        float e2 = __expf(sacc[qi][nt][2] - mnew);
        float e3 = __expf(sacc[qi][nt][3] - mnew);
        rsum += (e0 + e1) + (e2 + e3);
        ushort4v p4;
        p4.x = f2bf(e0); p4.y = f2bf(e1); p4.z = f2bf(e2); p4.w = f2bf(e3);
        afp[qi][nt] = p4;
      }
      rsum += __shfl_xor(rsum, 16);
      rsum += __shfl_xor(rsum, 32);
      lrun[qi] = lrun[qi] * alpha + rsum;
      mrun[qi] = mnew;
#pragma unroll
      for (int r = 0; r < 4; r++) {
        float ar = __shfl(alpha, quad * 4 + r);
#pragma unroll
        for (int dt = 0; dt < 8; dt++) oacc[qi][dt][r] *= ar;
      }
    }

#if HAVE_MFMA16
    // P in A-layout for 16x16x16: A[m=lq][k=quad*4+j]; V-frag read shared by both qi
#pragma unroll
    for (int ntk = 0; ntk < 4; ntk++) {
      int g = 2 * ntk + (quad >> 1);
      int go = (quad & 1) * 4;
#pragma unroll
      for (int dt = 0; dt < 8; dt++) {
        int row = dt * 16 + lq;
        ushort4v bf = *(const ushort4v*)&Vlds[row * 64 + (g ^ (row & 7)) * 8 + go];
        oacc[0][dt] = __builtin_amdgcn_mfma_f32_16x16x16bf16_1k(afp[0][ntk], bf, oacc[0][dt], 0, 0, 0);
        oacc[1][dt] = __builtin_amdgcn_mfma_f32_16x16x16bf16_1k(afp[1][ntk], bf, oacc[1][dt], 0, 0, 0);
      }
    }
#else
    // fallback: wave-local LDS round trip to x32 A-layout
    unsigned short* Pw = Plds + w * 16 * 72;
#pragma unroll
    for (int qi = 0; qi < 2; qi++) {
#pragma unroll
      for (int nt = 0; nt < 4; nt++)
        *(ushort4v*)&Pw[lq * 72 + nt * 16 + quad * 4] = afp[qi][nt];
#pragma unroll
      for (int kt = 0; kt < 2; kt++) {
        short8 af = *(const short8*)&Pw[lq * 72 + kt * 32 + quad * 8];
#pragma unroll
        for (int dt = 0; dt < 8; dt++) {
          int row = dt * 16 + lq;
          short8 bf = *(const short8*)&Vlds[row * 64 + ((kt * 4 + quad) ^ (lq & 7)) * 8];
          oacc[qi][dt] = __builtin_amdgcn_mfma_f32_16x16x32_bf16(af, bf, oacc[qi][dt], 0, 0, 0);
        }
      }
    }
#endif
  }

  float il[2][4];
#pragma unroll
  for (int qi = 0; qi < 2; qi++)
#pragma unroll
    for (int r = 0; r < 4; r++) il[qi][r] = 1.0f / __shfl(lrun[qi], quad * 4 + r);
#pragma unroll
  for (int qi = 0; qi < 2; qi++)
#pragma unroll
    for (int dt = 0; dt < 8; dt++)
#pragma unroll
      for (int r = 0; r < 4; r++)
        ao[(size_t)(i0 + w * 32 + qi * 16 + quad * 4 + r) * C + h * 128 + dt * 16 + lq] =
            f2bf(oacc[qi][dt][r] * il[qi][r]);
}

extern "C" void kernel_launch(void* const* d_in, const int* in_sizes, int n_in,
                              void* d_out, int out_size, void* d_ws, size_t ws_size,
                              hipStream_t stream) {
  const float* x    = (const float*)d_in[0];
  const float* rope = (const float*)d_in[1];
  const float* Wq   = (const float*)d_in[2];
  const float* bq   = (const float*)d_in[3];
  const float* Wk   = (const float*)d_in[4];
  const float* bk   = (const float*)d_in[5];
  const float* Wv   = (const float*)d_in[6];
  const float* bv   = (const float*)d_in[7];
  const float* qn_w = (const float*)d_in[8];
  const float* kn_w = (const float*)d_in[9];
  const float* Wo   = (const float*)d_in[10];
  const float* bo   = (const float*)d_in[11];
  float* out = (float*)d_out;

  unsigned short* xb  = (unsigned short*)d_ws;      // S*C
  unsigned short* wqb = xb + (size_t)S * C;         // 4*C*C (Wq,Wk,Wv,Wo contiguous)
  unsigned short* wob = wqb + (size_t)3 * C * C;
  unsigned short* qh  = wqb + (size_t)4 * C * C;    // [48][S][D]: q(16) k(16) v(16) heads
  unsigned short* kh  = qh + (size_t)S * C;
  unsigned short* vh  = kh + (size_t)S * C;
  unsigned short* vt  = vh + (size_t)S * C;         // [H][D][S]
  unsigned short* ao  = vt + (size_t)S * C;         // [S][C]
  float* bqkv = (float*)(ao + (size_t)S * C);       // 6144 floats

  cvt_kernel<<<S * C / 1024, 256, 0, stream>>>(x, xb, S * C);
  cvtw_kernel<<<dim3(C * C / 1024, 4), 256, 0, stream>>>(Wq, Wk, Wv, Wo, wqb);
  bias_concat<<<3 * C / 256, 256, 0, stream>>>(bq, bk, bv, bqkv);

  // fused QKV projection: N = 3*C = 6144, head-layout epilogue lands q/k/v contiguously
  gemm_bt<<<dim3(3 * C / 128, S / 128), 256, 0, stream>>>(xb, wqb, bqkv, (void*)qh, 3 * C, 1);

  rmsrope_kernel<<<(H * S) / 4, 256, 0, stream>>>(qh, qn_w, rope, SCALE);
  rmsrope_kernel<<<(H * S) / 4, 256, 0, stream>>>(kh, kn_w, rope, 1.0f);

  transpose_v<<<dim3(S / 64, D / 64, H), 256, 0, stream>>>(vh, vt);

  flash_kernel<<<dim3(S / 128, H), 256, 0, stream>>>(qh, kh, vt, ao);

  gemm_bt<<<dim3(C / 128, S / 128), 256, 0, stream>>>(ao, wob, bo, (void*)out, C, 0);
}

// Round 5
// 491.686 us; speedup vs baseline: 1.4187x; 1.1374x over previous
//
#include <hip/hip_runtime.h>

#define S 4096
#define C 2048
#define H 16
#define D 128
#define EPS 1.1920929e-07f
// 1/sqrt(128) * log2(e): fold both attention scale and exp->exp2 base change into q
#define QSCALE (0.08838834764831845f * 1.4426950408889634f)

typedef __attribute__((ext_vector_type(8))) short short8;            // 8 bf16 (MFMA x32 A/B)
typedef __attribute__((ext_vector_type(4))) float f32x4;             // MFMA C/D
typedef __attribute__((ext_vector_type(4))) unsigned short ushort4v; // 4 bf16 (MFMA x16 A/B)

#if __has_builtin(__builtin_amdgcn_mfma_f32_16x16x16bf16_1k)
#define HAVE_MFMA16 1
#else
#define HAVE_MFMA16 0
#endif

#if __has_builtin(__builtin_amdgcn_exp2f)
#define EXP2F __builtin_amdgcn_exp2f
#else
#define EXP2F exp2f
#endif

__device__ __forceinline__ unsigned short f2bf(float f) {
  unsigned int u = __builtin_bit_cast(unsigned int, f);
  u += 0x7fff + ((u >> 16) & 1);  // RNE
  return (unsigned short)(u >> 16);
}
__device__ __forceinline__ float bf2f(unsigned short v) {
  unsigned int u = ((unsigned int)v) << 16;
  return __builtin_bit_cast(float, u);
}
__device__ __forceinline__ unsigned int pkbf(float a, float b) {
  return (unsigned int)f2bf(a) | ((unsigned int)f2bf(b) << 16);
}
// truncate-pack two fp32 -> bf16 pair in ONE v_perm (no rounding; bias cancelled
// by computing the softmax denominator from these same truncated values)
__device__ __forceinline__ unsigned int pkbf_trunc(float a, float b) {
  return __builtin_amdgcn_perm(__builtin_bit_cast(unsigned int, b),
                               __builtin_bit_cast(unsigned int, a), 0x07060302);
}
__device__ __forceinline__ float lo16f(unsigned int d) {
  return __builtin_bit_cast(float, d << 16);
}
__device__ __forceinline__ float hi16f(unsigned int d) {
  return __builtin_bit_cast(float, d & 0xffff0000u);
}
// async global->LDS, 16B/lane; LDS dest = wave-uniform base + lane*16
__device__ __forceinline__ void gld16(const unsigned short* g, unsigned short* l) {
  __builtin_amdgcn_global_load_lds(
      (const __attribute__((address_space(1))) unsigned int*)g,
      (__attribute__((address_space(3))) unsigned int*)l, 16, 0, 0);
}

// ---------------- fp32 -> bf16 converts ----------------
__global__ void cvt_kernel(const float* __restrict__ src,
                           unsigned short* __restrict__ dst, int n) {
  int i = (blockIdx.x * 256 + threadIdx.x) * 4;
  if (i >= n) return;
  float4 v = *(const float4*)(src + i);
  ushort4 o;
  o.x = f2bf(v.x); o.y = f2bf(v.y); o.z = f2bf(v.z); o.w = f2bf(v.w);
  *(ushort4*)(dst + i) = o;
}
__global__ void cvtw_kernel(const float* __restrict__ w0, const float* __restrict__ w1,
                            const float* __restrict__ w2, const float* __restrict__ w3,
                            unsigned short* __restrict__ dst) {
  const float* srcs[4] = {w0, w1, w2, w3};
  const float* src = srcs[blockIdx.y];
  int i = (blockIdx.x * 256 + threadIdx.x) * 4;
  float4 v = *(const float4*)(src + i);
  ushort4 o;
  o.x = f2bf(v.x); o.y = f2bf(v.y); o.z = f2bf(v.z); o.w = f2bf(v.w);
  *(ushort4*)(dst + (size_t)blockIdx.y * C * C + i) = o;
}
__global__ void bias_concat(const float* __restrict__ bq, const float* __restrict__ bk,
                            const float* __restrict__ bv, float* __restrict__ dst) {
  int i = blockIdx.x * 256 + threadIdx.x;  // 0..6143
  const float* s = (i < C) ? bq : ((i < 2 * C) ? bk : bv);
  dst[i] = s[i & (C - 1)];
}

// ---------------- bf16 GEMM: out[m][n] = sum_k A[m][k]*B[n][k] + bias[n]
// mode 0: fp32 out [M][N] direct.
// mode 1 (QKV, N=6144): LDS-bounce epilogue with coalesced 16B stores.
//   gh=n0>>7: gh<16 -> qh[gh][m][d]; gh<32 -> kh[gh-16][m][d]; else vt[gh-32][d][m] (transposed).
__global__ __launch_bounds__(256) void gemm_bt(const unsigned short* __restrict__ A,
                                               const unsigned short* __restrict__ B,
                                               const float* __restrict__ bias,
                                               float* __restrict__ outf,
                                               unsigned short* __restrict__ qh,
                                               unsigned short* __restrict__ kh,
                                               unsigned short* __restrict__ vt,
                                               int N, int mode) {
  __shared__ __align__(16) unsigned short U[128 * 136];  // main loop uses first 32 KB
  unsigned short* Al = U;             // 128*64
  unsigned short* Bl = U + 128 * 64;  // 128*64
  const int t = threadIdx.x, w = t >> 6, lane = t & 63;
  const int lq = lane & 15, quad = lane >> 4;
  const int wm = w & 1, wn = w >> 1;
  const int m0 = blockIdx.y * 128, n0 = blockIdx.x * 128;
  f32x4 acc[4][4] = {};
  float biasv[4];
#pragma unroll
  for (int nt = 0; nt < 4; nt++) biasv[nt] = bias[n0 + wn * 64 + nt * 16 + lq];
  const int sr = lane >> 3, sg = lane & 7;
  for (int k0 = 0; k0 < C; k0 += 64) {
    __syncthreads();
#pragma unroll
    for (int p = 0; p < 4; p++) {
      int row = w * 32 + p * 8 + sr;
      int c = sg ^ (row & 7);  // swizzle on the global source; LDS dest lane-linear
      gld16(A + (size_t)(m0 + row) * C + k0 + c * 8, &Al[(w * 32 + p * 8) * 64]);
      gld16(B + (size_t)(n0 + row) * C + k0 + c * 8, &Bl[(w * 32 + p * 8) * 64]);
    }
    __syncthreads();
#pragma unroll
    for (int ks = 0; ks < 2; ks++) {
      short8 af[4], bf[4];
#pragma unroll
      for (int mt = 0; mt < 4; mt++) {
        int row = wm * 64 + mt * 16 + lq;
        af[mt] = *(const short8*)&Al[row * 64 + ((ks * 4 + quad) ^ (lq & 7)) * 8];
      }
#pragma unroll
      for (int nt = 0; nt < 4; nt++) {
        int row = wn * 64 + nt * 16 + lq;
        bf[nt] = *(const short8*)&Bl[row * 64 + ((ks * 4 + quad) ^ (lq & 7)) * 8];
      }
#pragma unroll
      for (int mt = 0; mt < 4; mt++)
#pragma unroll
        for (int nt = 0; nt < 4; nt++)
          acc[mt][nt] = __builtin_amdgcn_mfma_f32_16x16x32_bf16(af[mt], bf[nt], acc[mt][nt], 0, 0, 0);
    }
  }

  if (mode == 0) {
#pragma unroll
    for (int mt = 0; mt < 4; mt++)
#pragma unroll
      for (int nt = 0; nt < 4; nt++) {
        int n = n0 + wn * 64 + nt * 16 + lq;
#pragma unroll
        for (int r = 0; r < 4; r++) {
          int m = m0 + wm * 64 + mt * 16 + quad * 4 + r;  // C/D: col=lane&15, row=quad*4+r
          outf[(size_t)m * N + n] = acc[mt][nt][r] + biasv[nt];
        }
      }
    return;
  }

  // ---- mode 1: LDS bounce, coalesced stores ----
  const int gh = n0 >> 7;
  __syncthreads();
  const int rr = t >> 4, ck = t & 15;
  if (gh < 32) {
    // bounce [m][d], stride 136 shorts (16B-aligned rows)
#pragma unroll
    for (int mt = 0; mt < 4; mt++)
#pragma unroll
      for (int nt = 0; nt < 4; nt++) {
        int dloc = wn * 64 + nt * 16 + lq;
#pragma unroll
        for (int r = 0; r < 4; r++)
          U[(wm * 64 + mt * 16 + quad * 4 + r) * 136 + dloc] = f2bf(acc[mt][nt][r] + biasv[nt]);
      }
    __syncthreads();
    unsigned short* dst = ((gh < 16) ? qh : kh) + (size_t)(gh & 15) * S * D;
#pragma unroll
    for (int p = 0; p < 8; p++) {
      int m = p * 16 + rr;
      uint4 vv = *(const uint4*)&U[m * 136 + ck * 8];
      *(uint4*)(dst + (size_t)(m0 + m) * D + ck * 8) = vv;
    }
  } else {
    // v: bounce transposed [d][m], dword-packed writes
#pragma unroll
    for (int mt = 0; mt < 4; mt++)
#pragma unroll
      for (int nt = 0; nt < 4; nt++) {
        int dloc = wn * 64 + nt * 16 + lq;
        int mloc = wm * 64 + mt * 16 + quad * 4;
        *(unsigned int*)&U[dloc * 136 + mloc] =
            pkbf(acc[mt][nt][0] + biasv[nt], acc[mt][nt][1] + biasv[nt]);
        *(unsigned int*)&U[dloc * 136 + mloc + 2] =
            pkbf(acc[mt][nt][2] + biasv[nt], acc[mt][nt][3] + biasv[nt]);
      }
    __syncthreads();
    unsigned short* dst = vt + (size_t)(gh - 32) * D * S;
#pragma unroll
    for (int p = 0; p < 8; p++) {
      int d = p * 16 + rr;
      uint4 vv = *(const uint4*)&U[d * 136 + ck * 8];
      *(uint4*)(dst + (size_t)d * S + m0 + ck * 8) = vv;
    }
  }
}

// ---------------- fused RMSNorm + rotary, in place on [H][S][D]; y=0 -> q, y=1 -> k ----
__global__ __launch_bounds__(256) void rmsrope_kernel(unsigned short* __restrict__ qh,
                                                      unsigned short* __restrict__ kh,
                                                      const float* __restrict__ qn_w,
                                                      const float* __restrict__ kn_w,
                                                      const float* __restrict__ rope) {
  const int which = blockIdx.y;
  unsigned short* io = which ? kh : qh;
  const float* wgt = which ? kn_w : qn_w;
  const float scale = which ? 1.0f : QSCALE;
  int wid = (blockIdx.x * 256 + threadIdx.x) >> 6;  // wave id = h*S + s
  int lane = threadIdx.x & 63;
  int s = wid & (S - 1);
  unsigned short* row = io + (size_t)wid * D;
  unsigned int pr = *(unsigned int*)(row + lane * 2);
  float a = bf2f((unsigned short)(pr & 0xffff));
  float b = bf2f((unsigned short)(pr >> 16));
  float ss = a * a + b * b;
  for (int m = 1; m < 64; m <<= 1) ss += __shfl_xor(ss, m);
  float inv = rsqrtf(ss * (1.0f / 128.0f) + EPS) * scale;
  float2 wv = *(const float2*)(wgt + lane * 2);
  float an = a * inv * wv.x, bn = b * inv * wv.y;
  float4 r = *(const float4*)(rope + (size_t)s * 256 + lane * 4);
  *(unsigned int*)(row + lane * 2) = pkbf(r.x * an + r.y * bn, r.z * an + r.w * bn);
}

// ---------------- flash attention: BM=32/wave (128/block), BN=128 j-tiles.
// No online max: scores are bounded (rmsnormed q,k; |s|max ~ 12 << fp32 exp range),
// so P = exp2(s*log2e) directly (log2e pre-folded into q), denominator from the
// truncated-bf16 P values (bias cancels in P/sum).
__global__ __launch_bounds__(256, 2) void flash_kernel(const unsigned short* __restrict__ qh,
                                                       const unsigned short* __restrict__ kh,
                                                       const unsigned short* __restrict__ vt,
                                                       unsigned short* __restrict__ ao) {
  __shared__ __align__(16) unsigned short Klds[128 * 128];  // [j][d], swizzled (32 KB)
  __shared__ __align__(16) unsigned short Vlds[128 * 128];  // [d][j], swizzled (32 KB)
  const int h = blockIdx.y, i0 = blockIdx.x * 128;
  const int t = threadIdx.x, w = t >> 6, lane = t & 63;
  const int lq = lane & 15, quad = lane >> 4;

  // Q as MFMA B-operand: n=lq (q row), k=quad*8+j (d). scale+log2e pre-folded.
  const unsigned short* Qbase = qh + ((size_t)h * S + i0 + w * 32 + lq) * D;
  short8 qfrag[2][4];
#pragma unroll
  for (int qi = 0; qi < 2; qi++)
#pragma unroll
    for (int kt = 0; kt < 4; kt++)
      qfrag[qi][kt] = *(const short8*)(Qbase + (size_t)qi * 16 * D + kt * 32 + quad * 8);

  f32x4 oacc[2][8] = {};
  float lrun[2] = {0.0f, 0.0f};
  const unsigned short* Kbase = kh + (size_t)h * S * D;
  const unsigned short* Vbase = vt + (size_t)h * D * S;

  const int kr = lane >> 4, kg = lane & 15;  // staging: 4 rows/call, 16 groups/row

  for (int j0 = 0; j0 < S; j0 += 128) {
    __syncthreads();
#pragma unroll
    for (int p = 0; p < 8; p++) {
      int krow = w * 32 + p * 4 + kr;
      gld16(Kbase + (size_t)(j0 + krow) * D + (kg ^ (krow & 7)) * 8,
            &Klds[(w * 32 + p * 4) * 128]);
      gld16(Vbase + (size_t)krow * S + j0 + (kg ^ (krow & 7)) * 8,
            &Vlds[(w * 32 + p * 4) * 128]);
    }
    __syncthreads();

    // S^T = K·Q^T : sacc[qi][nt][r] = s*log2e for [q=lq(+16qi)][j = j0+nt*16+quad*4+r]
    f32x4 sacc[2][8] = {};
#pragma unroll
    for (int kt = 0; kt < 4; kt++)
#pragma unroll
      for (int nt = 0; nt < 8; nt++) {
        int row = nt * 16 + lq;
        short8 af = *(const short8*)&Klds[row * 128 + (((kt * 4 + quad) ^ (row & 7)) * 8)];
        sacc[0][nt] = __builtin_amdgcn_mfma_f32_16x16x32_bf16(af, qfrag[0][kt], sacc[0][nt], 0, 0, 0);
        sacc[1][nt] = __builtin_amdgcn_mfma_f32_16x16x32_bf16(af, qfrag[1][kt], sacc[1][nt], 0, 0, 0);
      }

    // softmax numerators: exp2, truncate-pack to bf16, sum the truncated values
    unsigned int pd[2][8][2];
#pragma unroll
    for (int qi = 0; qi < 2; qi++) {
      float rsum = 0.0f;
#pragma unroll
      for (int nt = 0; nt < 8; nt++) {
        float e0 = EXP2F(sacc[qi][nt][0]);
        float e1 = EXP2F(sacc[qi][nt][1]);
        float e2 = EXP2F(sacc[qi][nt][2]);
        float e3 = EXP2F(sacc[qi][nt][3]);
        unsigned int d0 = pkbf_trunc(e0, e1);
        unsigned int d1 = pkbf_trunc(e2, e3);
        pd[qi][nt][0] = d0;
        pd[qi][nt][1] = d1;
        rsum += (lo16f(d0) + hi16f(d0)) + (lo16f(d1) + hi16f(d1));
      }
      lrun[qi] += rsum;
    }

#if HAVE_MFMA16
    // O += P·V with x16 MFMA: P already in A-layout (m=lq, k=quad*4+r); V-frags shared by qi
#pragma unroll
    for (int ntk = 0; ntk < 8; ntk++) {
      ushort4v a0 = __builtin_bit_cast(ushort4v, make_uint2(pd[0][ntk][0], pd[0][ntk][1]));
      ushort4v a1 = __builtin_bit_cast(ushort4v, make_uint2(pd[1][ntk][0], pd[1][ntk][1]));
      int g = 2 * ntk + (quad >> 1), go = (quad & 1) * 4;
#pragma unroll
      for (int dt = 0; dt < 8; dt++) {
        int row = dt * 16 + lq;
        ushort4v bf = *(const ushort4v*)&Vlds[row * 128 + ((g ^ (row & 7)) * 8) + go];
        oacc[0][dt] = __builtin_amdgcn_mfma_f32_16x16x16bf16_1k(a0, bf, oacc[0][dt], 0, 0, 0);
        oacc[1][dt] = __builtin_amdgcn_mfma_f32_16x16x16bf16_1k(a1, bf, oacc[1][dt], 0, 0, 0);
      }
    }
#else
    // fallback: LDS round trip to x32 A-layout (reuse Klds; all QK reads are done)
    __syncthreads();
    {
      unsigned short* Pw = Klds + w * 16 * 136;
#pragma unroll
      for (int qi = 0; qi < 2; qi++) {
#pragma unroll
        for (int nt = 0; nt < 8; nt++) {
          *(unsigned int*)&Pw[lq * 136 + nt * 16 + quad * 4] = pd[qi][nt][0];
          *(unsigned int*)&Pw[lq * 136 + nt * 16 + quad * 4 + 2] = pd[qi][nt][1];
        }
#pragma unroll
        for (int kt = 0; kt < 4; kt++) {
          short8 af = *(const short8*)&Pw[lq * 136 + kt * 32 + quad * 8];
#pragma unroll
          for (int dt = 0; dt < 8; dt++) {
            int row = dt * 16 + lq;
            short8 bf = *(const short8*)&Vlds[row * 128 + (((kt * 4 + quad) ^ (row & 7)) * 8)];
            oacc[qi][dt] = __builtin_amdgcn_mfma_f32_16x16x32_bf16(af, bf, oacc[qi][dt], 0, 0, 0);
          }
        }
      }
    }
#endif
  }

  // final: reduce denominators across quads once, divide, store
#pragma unroll
  for (int qi = 0; qi < 2; qi++) {
    lrun[qi] += __shfl_xor(lrun[qi], 16);
    lrun[qi] += __shfl_xor(lrun[qi], 32);
  }
  float il[2][4];
#pragma unroll
  for (int qi = 0; qi < 2; qi++)
#pragma unroll
    for (int r = 0; r < 4; r++) il[qi][r] = 1.0f / __shfl(lrun[qi], quad * 4 + r);
#pragma unroll
  for (int qi = 0; qi < 2; qi++)
#pragma unroll
    for (int dt = 0; dt < 8; dt++)
#pragma unroll
      for (int r = 0; r < 4; r++)
        ao[(size_t)(i0 + w * 32 + qi * 16 + quad * 4 + r) * C + h * 128 + dt * 16 + lq] =
            f2bf(oacc[qi][dt][r] * il[qi][r]);
}

extern "C" void kernel_launch(void* const* d_in, const int* in_sizes, int n_in,
                              void* d_out, int out_size, void* d_ws, size_t ws_size,
                              hipStream_t stream) {
  const float* x    = (const float*)d_in[0];
  const float* rope = (const float*)d_in[1];
  const float* Wq   = (const float*)d_in[2];
  const float* bq   = (const float*)d_in[3];
  const float* Wk   = (const float*)d_in[4];
  const float* bk   = (const float*)d_in[5];
  const float* Wv   = (const float*)d_in[6];
  const float* bv   = (const float*)d_in[7];
  const float* qn_w = (const float*)d_in[8];
  const float* kn_w = (const float*)d_in[9];
  const float* Wo   = (const float*)d_in[10];
  const float* bo   = (const float*)d_in[11];
  float* out = (float*)d_out;

  unsigned short* xb  = (unsigned short*)d_ws;      // S*C
  unsigned short* wqb = xb + (size_t)S * C;         // 4*C*C (Wq,Wk,Wv,Wo contiguous)
  unsigned short* wob = wqb + (size_t)3 * C * C;
  unsigned short* qh  = wqb + (size_t)4 * C * C;    // [H][S][D]
  unsigned short* kh  = qh + (size_t)S * C;         // [H][S][D]
  unsigned short* vt  = kh + (size_t)S * C;         // [H][D][S] (written transposed)
  unsigned short* ao  = vt + (size_t)S * C;         // [S][C]
  float* bqkv = (float*)(ao + (size_t)S * C);       // 6144 floats

  cvt_kernel<<<S * C / 1024, 256, 0, stream>>>(x, xb, S * C);
  cvtw_kernel<<<dim3(C * C / 1024, 4), 256, 0, stream>>>(Wq, Wk, Wv, Wo, wqb);
  bias_concat<<<3 * C / 256, 256, 0, stream>>>(bq, bk, bv, bqkv);

  // fused QKV projection; epilogue writes q/k head-major and v directly transposed
  gemm_bt<<<dim3(3 * C / 128, S / 128), 256, 0, stream>>>(
      xb, wqb, bqkv, nullptr, qh, kh, vt, 3 * C, 1);

  rmsrope_kernel<<<dim3((H * S) / 4, 2), 256, 0, stream>>>(qh, kh, qn_w, kn_w, rope);

  flash_kernel<<<dim3(S / 128, H), 256, 0, stream>>>(qh, kh, vt, ao);

  gemm_bt<<<dim3(C / 128, S / 128), 256, 0, stream>>>(
      ao, wob, bo, out, nullptr, nullptr, nullptr, C, 0);
}